// Round 1
// baseline (778.311 us; speedup 1.0000x reference)
//
#include <hip/hip_runtime.h>
#include <cstdint>

// ---------------- problem constants ----------------
static constexpr int B_   = 8192;
static constexpr int NW_  = 192;                 // NS + NV
static constexpr int KSC  = 16384 + 4096;        // scalar-path K (x0x0 + dots)
static constexpr int KVE  = 8192 + 4096;         // vector-path K (v011 + v111)
static constexpr int SSC  = KSC / 32;            // 640 K-steps
static constexpr int SVE  = KVE / 32;            // 384 K-steps

typedef __attribute__((ext_vector_type(8))) short s8v;
typedef __attribute__((ext_vector_type(4))) float f4v;

#define DI __device__ __forceinline__

DI short f2bf(float f) {
  unsigned u = __builtin_bit_cast(unsigned, f);
  u += 0x7FFFu + ((u >> 16) & 1u);               // round-to-nearest-even
  return (short)(u >> 16);
}

// ---------------- prep: x1 planes x1p[i][b][v] (f32) ----------------
__global__ void prep_x1(const float* __restrict__ x, float* __restrict__ x1p) {
  int t = blockIdx.x * blockDim.x + threadIdx.x;  // 3*8192*64 threads exactly
  int i = t / (B_ * 64);
  int rm = t % (B_ * 64);
  int b = rm / 64, v = rm % 64;
  x1p[t] = x[(size_t)b * 320 + 128 + v * 3 + i];
}

// ---------------- prep: scalar-path weights, fragment-packed bf16 ----------------
// Wf[kt][nt(12)][lane(64)][j(8)] = W[k = kt*32 + (lane>>4)*8 + j][n = nt*16 + (lane&15)]
__global__ void prep_wsc(const float* __restrict__ w000, const float* __restrict__ w110,
                         short* __restrict__ wf) {
  int g = blockIdx.x * blockDim.x + threadIdx.x;  // 20480*192/8 threads exactly
  int l = g & 63;
  int nt = (g >> 6) % 12;
  int kt = g / (64 * 12);
  int n = nt * 16 + (l & 15);
  int kbase = kt * 32 + ((l >> 4) << 3);
  const float s000 = 1.0f / (128.0f * 1.41421356237f);   // (1/N0) * inv_sqrt2
  const float s110 = 1.0f / (64.0f * 2.44948974968f);    // (1/(N1*sqrt3)) * inv_sqrt2
  s8v o;
#pragma unroll
  for (int j = 0; j < 8; ++j) {
    int k = kbase + j;
    float v = (k < 16384) ? w000[(size_t)k * NW_ + n] * s000
                          : w110[(size_t)(k - 16384) * NW_ + n] * s110;
    o[j] = f2bf(v);
  }
  *(s8v*)(wf + (size_t)g * 8) = o;
}

// ---------------- prep: vector-path weights, fragment-packed bf16 ----------------
__global__ void prep_wvec(const float* __restrict__ w011, const float* __restrict__ w111,
                          short* __restrict__ wf) {
  int g = blockIdx.x * blockDim.x + threadIdx.x;  // 12288*64/8 threads exactly
  int l = g & 63;
  int nt = (g >> 6) & 3;
  int kt = g >> 8;
  int n = nt * 16 + (l & 15);
  int kbase = kt * 32 + ((l >> 4) << 3);
  const float sv = 1.0f / 128.0f;  // both v011 and v111 total scales reduce to 1/128
  s8v o;
#pragma unroll
  for (int j = 0; j < 8; ++j) {
    int k = kbase + j;
    float v = (k < 8192) ? w011[(size_t)k * 64 + n] * sv
                         : w111[(size_t)(k - 8192) * 64 + n] * sv;
    o[j] = f2bf(v);
  }
  *(s8v*)(wf + (size_t)g * 8) = o;
}

// ---------------- scalar-path GEMM: C[8192,192] += A(gen) * Wsc ----------------
// wave tile 64x96, block = Mtile(64 rows) x Kchunk; 16-way split-K via atomics
__global__ __launch_bounds__(256, 2)
void gemm_sc(const float* __restrict__ x, const float* __restrict__ x1p,
             const short* __restrict__ wf, float* __restrict__ acc_out) {
  const int lane = threadIdx.x & 63;
  const int wv = threadIdx.x >> 6;
  const int nh = wv & 1;          // n-half: 0 -> cols 0..95, 1 -> 96..191
  const int kh = wv >> 1;         // k-half within block chunk
  const int mt = blockIdx.x & 127;
  const int kb = blockIdx.x >> 7; // 0..7
  const int b0 = mt * 64;
  const int q = lane >> 4, r = lane & 15;
  const int s0 = kb * 80 + kh * 40;   // 40 steps per wave (640 total / 16)

  f4v acc[4][6];
#pragma unroll
  for (int mf = 0; mf < 4; ++mf)
#pragma unroll
    for (int nf = 0; nf < 6; ++nf) acc[mf][nf] = f4v{0.f, 0.f, 0.f, 0.f};

  for (int s = s0; s < s0 + 40; ++s) {
    const int k0 = s * 32;
    s8v bfr[6];
#pragma unroll
    for (int nf = 0; nf < 6; ++nf) {
      int nt = nh * 6 + nf;
      bfr[nf] = *(const s8v*)(wf + (((size_t)s * 12 + nt) * 64 + lane) * 8);
    }
    s8v afr[4];
    if (k0 < 16384) {
      // A[m][k] = x0[m][u] * x0[m][v],  k = u*128 + v
      const int u = k0 >> 7;
      const int vb = (k0 & 127) + q * 8;
#pragma unroll
      for (int mf = 0; mf < 4; ++mf) {
        const float* xrow = x + (size_t)(b0 + mf * 16 + r) * 320;
        float xu = xrow[u];
        f4v v0 = *(const f4v*)(xrow + vb);
        f4v v1 = *(const f4v*)(xrow + vb + 4);
        s8v a;
        a[0] = f2bf(xu * v0.x); a[1] = f2bf(xu * v0.y);
        a[2] = f2bf(xu * v0.z); a[3] = f2bf(xu * v0.w);
        a[4] = f2bf(xu * v1.x); a[5] = f2bf(xu * v1.y);
        a[6] = f2bf(xu * v1.z); a[7] = f2bf(xu * v1.w);
        afr[mf] = a;
      }
    } else {
      // A[m][k] = dot3(x1[m][u], x1[m][v]),  k-16384 = u*64 + v
      const int kk = k0 - 16384;
      const int u = kk >> 6;
      const int vb = (kk & 63) + q * 8;
#pragma unroll
      for (int mf = 0; mf < 4; ++mf) {
        const int row = b0 + mf * 16 + r;
        float av[8] = {0.f, 0.f, 0.f, 0.f, 0.f, 0.f, 0.f, 0.f};
#pragma unroll
        for (int i = 0; i < 3; ++i) {
          const float* p = x1p + ((size_t)i * B_ + row) * 64;
          float pu = p[u];
          f4v v0 = *(const f4v*)(p + vb);
          f4v v1 = *(const f4v*)(p + vb + 4);
          av[0] += pu * v0.x; av[1] += pu * v0.y;
          av[2] += pu * v0.z; av[3] += pu * v0.w;
          av[4] += pu * v1.x; av[5] += pu * v1.y;
          av[6] += pu * v1.z; av[7] += pu * v1.w;
        }
        s8v a;
#pragma unroll
        for (int j = 0; j < 8; ++j) a[j] = f2bf(av[j]);
        afr[mf] = a;
      }
    }
#pragma unroll
    for (int mf = 0; mf < 4; ++mf)
#pragma unroll
      for (int nf = 0; nf < 6; ++nf)
        acc[mf][nf] = __builtin_amdgcn_mfma_f32_16x16x32_bf16(afr[mf], bfr[nf], acc[mf][nf], 0, 0, 0);
  }

#pragma unroll
  for (int mf = 0; mf < 4; ++mf)
#pragma unroll
    for (int nf = 0; nf < 6; ++nf) {
      int n = (nh * 6 + nf) * 16 + r;
#pragma unroll
      for (int reg = 0; reg < 4; ++reg) {
        int row = b0 + mf * 16 + q * 4 + reg;
        atomicAdd(&acc_out[(size_t)row * NW_ + n], acc[mf][nf][reg]);
      }
    }
}

// ---------------- vector-path GEMM: C[3*8192, 64] += A(gen) * Wvec ----------------
// rows r = i*8192 + b; wave tile 64x64; 16-way split-K
__global__ __launch_bounds__(256, 2)
void gemm_vec(const float* __restrict__ x, const float* __restrict__ x1p,
              const short* __restrict__ wf, float* __restrict__ acc_out) {
  const int lane = threadIdx.x & 63;
  const int wv = threadIdx.x >> 6;   // k sub-chunk
  const int mt = blockIdx.x % 384;
  const int kb = blockIdx.x / 384;   // 0..3
  const int ip = mt >> 7;            // plane (output vector component)
  const int b0 = (mt & 127) * 64;
  const int q = lane >> 4, r = lane & 15;
  const int s0 = kb * 96 + wv * 24;  // 24 steps per wave (384 total / 16)
  const int i1 = (ip + 1) % 3, i2 = (ip + 2) % 3;

  f4v acc[4][4];
#pragma unroll
  for (int mf = 0; mf < 4; ++mf)
#pragma unroll
    for (int nf = 0; nf < 4; ++nf) acc[mf][nf] = f4v{0.f, 0.f, 0.f, 0.f};

  for (int s = s0; s < s0 + 24; ++s) {
    const int k0 = s * 32;
    s8v bfr[4];
#pragma unroll
    for (int nf = 0; nf < 4; ++nf)
      bfr[nf] = *(const s8v*)(wf + (((size_t)s * 4 + nf) * 64 + lane) * 8);
    s8v afr[4];
    if (k0 < 8192) {
      // A = x0[b][u] * x1[b][v][ip],  k = u*64 + v
      const int u = k0 >> 6;
      const int vb = (k0 & 63) + q * 8;
#pragma unroll
      for (int mf = 0; mf < 4; ++mf) {
        const int b = b0 + mf * 16 + r;
        float xu = x[(size_t)b * 320 + u];
        const float* p = x1p + ((size_t)ip * B_ + b) * 64;
        f4v v0 = *(const f4v*)(p + vb);
        f4v v1 = *(const f4v*)(p + vb + 4);
        s8v a;
        a[0] = f2bf(xu * v0.x); a[1] = f2bf(xu * v0.y);
        a[2] = f2bf(xu * v0.z); a[3] = f2bf(xu * v0.w);
        a[4] = f2bf(xu * v1.x); a[5] = f2bf(xu * v1.y);
        a[6] = f2bf(xu * v1.z); a[7] = f2bf(xu * v1.w);
        afr[mf] = a;
      }
    } else {
      // A = x1[b][u][i1]*x1[b][v][i2] - x1[b][u][i2]*x1[b][v][i1]  (cross comp ip)
      const int kk = k0 - 8192;
      const int u = kk >> 6;
      const int vb = (kk & 63) + q * 8;
#pragma unroll
      for (int mf = 0; mf < 4; ++mf) {
        const int b = b0 + mf * 16 + r;
        const float* p1 = x1p + ((size_t)i1 * B_ + b) * 64;
        const float* p2 = x1p + ((size_t)i2 * B_ + b) * 64;
        float u1 = p1[u], u2 = p2[u];
        f4v w0 = *(const f4v*)(p2 + vb);
        f4v w1 = *(const f4v*)(p2 + vb + 4);
        f4v z0 = *(const f4v*)(p1 + vb);
        f4v z1 = *(const f4v*)(p1 + vb + 4);
        s8v a;
        a[0] = f2bf(u1 * w0.x - u2 * z0.x); a[1] = f2bf(u1 * w0.y - u2 * z0.y);
        a[2] = f2bf(u1 * w0.z - u2 * z0.z); a[3] = f2bf(u1 * w0.w - u2 * z0.w);
        a[4] = f2bf(u1 * w1.x - u2 * z1.x); a[5] = f2bf(u1 * w1.y - u2 * z1.y);
        a[6] = f2bf(u1 * w1.z - u2 * z1.z); a[7] = f2bf(u1 * w1.w - u2 * z1.w);
        afr[mf] = a;
      }
    }
#pragma unroll
    for (int mf = 0; mf < 4; ++mf)
#pragma unroll
      for (int nf = 0; nf < 4; ++nf)
        acc[mf][nf] = __builtin_amdgcn_mfma_f32_16x16x32_bf16(afr[mf], bfr[nf], acc[mf][nf], 0, 0, 0);
  }

#pragma unroll
  for (int mf = 0; mf < 4; ++mf)
#pragma unroll
    for (int nf = 0; nf < 4; ++nf) {
      int n = nf * 16 + r;
#pragma unroll
      for (int reg = 0; reg < 4; ++reg) {
        int rr = ip * B_ + b0 + mf * 16 + q * 4 + reg;
        atomicAdd(&acc_out[(size_t)rr * 64 + n], acc[mf][nf][reg]);
      }
    }
}

// ---------------- epilogue: silu / sigmoid-gating, interleaved output ----------------
__global__ void epilogue(const float* __restrict__ sc, const float* __restrict__ ve,
                         float* __restrict__ out) {
  int t = blockIdx.x * blockDim.x + threadIdx.x;  // B*192 threads exactly
  int b = t / NW_, c = t % NW_;
  float v = sc[t];
  float sg = 1.0f / (1.0f + __expf(-v));
  if (c < 128) {
    out[(size_t)b * 320 + c] = v * sg;            // silu
  } else {
    int w = c - 128;
#pragma unroll
    for (int i = 0; i < 3; ++i) {
      float vv = ve[((size_t)i * B_ + b) * 64 + w];
      out[(size_t)b * 320 + 128 + w * 3 + i] = vv * sg;
    }
  }
}

// ---------------- launch ----------------
extern "C" void kernel_launch(void* const* d_in, const int* in_sizes, int n_in,
                              void* d_out, int out_size, void* d_ws, size_t ws_size,
                              hipStream_t stream) {
  const float* x    = (const float*)d_in[0];
  const float* w000 = (const float*)d_in[1];
  const float* w110 = (const float*)d_in[2];
  const float* w011 = (const float*)d_in[3];
  const float* w111 = (const float*)d_in[4];
  float* out = (float*)d_out;

  char* ws = (char*)d_ws;
  float* acc_sc = (float*)ws;                     // 8192*192*4  = 6,291,456 B
  float* acc_ve = (float*)(ws + 6291456);         // 3*8192*64*4 = 6,291,456 B
  float* x1p    = (float*)(ws + 12582912);        // 3*8192*64*4 = 6,291,456 B
  short* wsc    = (short*)(ws + 18874368);        // 20480*192*2 = 7,864,320 B
  short* wve    = (short*)(ws + 26738688);        // 12288*64*2  = 1,572,864 B
  // total ws use: 28,311,552 B

  (void)hipMemsetAsync(acc_sc, 0, 2 * 6291456, stream);  // zero both accumulators
  prep_x1 <<<6144, 256, 0, stream>>>(x, x1p);
  prep_wsc<<<1920, 256, 0, stream>>>(w000, w110, wsc);
  prep_wvec<<<384,  256, 0, stream>>>(w011, w111, wve);
  gemm_sc <<<1024, 256, 0, stream>>>(x, x1p, wsc, acc_sc);
  gemm_vec<<<1536, 256, 0, stream>>>(x, x1p, wve, acc_ve);
  epilogue<<<6144, 256, 0, stream>>>(acc_sc, acc_ve, out);
}

// Round 2
// 354.730 us; speedup vs baseline: 2.1941x; 2.1941x over previous
//
#include <hip/hip_runtime.h>
#include <cstdint>

// ---------------- problem constants ----------------
static constexpr int B_  = 8192;
static constexpr int NW_ = 192;                 // NS + NV

typedef __attribute__((ext_vector_type(8))) short s8v;
typedef __attribute__((ext_vector_type(4))) float f4v;
typedef __attribute__((ext_vector_type(4))) int i4v;
typedef __attribute__((ext_vector_type(4))) unsigned u4v;

#define DI __device__ __forceinline__

DI short f2bf_rne(float f) {
  unsigned u = __builtin_bit_cast(unsigned, f);
  u += 0x7FFFu + ((u >> 16) & 1u);               // round-to-nearest-even
  return (short)(u >> 16);
}
DI float bf2f(unsigned short h) {
  unsigned u = ((unsigned)h) << 16;
  return __builtin_bit_cast(float, u);
}
DI float ibitsf(int u) { return __builtin_bit_cast(float, u); }
// pack bf16(lo), bf16(hi) with round-half-up: 2 adds + 1 v_perm
DI unsigned rpack(float lo, float hi) {
  unsigned ua = __builtin_bit_cast(unsigned, lo) + 0x8000u;
  unsigned ub = __builtin_bit_cast(unsigned, hi) + 0x8000u;
  return __builtin_amdgcn_perm(ub, ua, 0x07060302u);
}

// ---------------- prep: scalar-path weights, fragment-packed bf16 ----------------
// Wf[kt][nt(12)][lane(64)][j(8)] = W[k = kt*32 + (lane>>4)*8 + j][n = nt*16 + (lane&15)]
__global__ void prep_wsc(const float* __restrict__ w000, const float* __restrict__ w110,
                         short* __restrict__ wf) {
  int g = blockIdx.x * blockDim.x + threadIdx.x;  // 20480*192/8 threads exactly
  int l = g & 63;
  int nt = (g >> 6) % 12;
  int kt = g / (64 * 12);
  int n = nt * 16 + (l & 15);
  int kbase = kt * 32 + ((l >> 4) << 3);
  const float s000 = 1.0f / (128.0f * 1.41421356237f);   // (1/N0) * inv_sqrt2
  const float s110 = 1.0f / (64.0f * 2.44948974968f);    // (1/(N1*sqrt6 total))
  s8v o;
#pragma unroll
  for (int j = 0; j < 8; ++j) {
    int k = kbase + j;
    float v = (k < 16384) ? w000[(size_t)k * NW_ + n] * s000
                          : w110[(size_t)(k - 16384) * NW_ + n] * s110;
    o[j] = f2bf_rne(v);
  }
  *(s8v*)(wf + (size_t)g * 8) = o;
}

// ---------------- prep: vector-path weights, fragment-packed bf16 ----------------
__global__ void prep_wvec(const float* __restrict__ w011, const float* __restrict__ w111,
                          short* __restrict__ wf) {
  int g = blockIdx.x * blockDim.x + threadIdx.x;  // 12288*64/8 threads exactly
  int l = g & 63;
  int nt = (g >> 6) & 3;
  int kt = g >> 8;
  int n = nt * 16 + (l & 15);
  int kbase = kt * 32 + ((l >> 4) << 3);
  const float sv = 1.0f / 128.0f;  // both v011 and v111 total scales reduce to 1/128
  s8v o;
#pragma unroll
  for (int j = 0; j < 8; ++j) {
    int k = kbase + j;
    float v = (k < 8192) ? w011[(size_t)k * 64 + n] * sv
                         : w111[(size_t)(k - 8192) * 64 + n] * sv;
    o[j] = f2bf_rne(v);
  }
  *(s8v*)(wf + (size_t)g * 8) = o;
}

// ---------------- shared LDS staging: 64 rows of x ----------------
// X0[row][c] f32, stride 132 (pad 4)  : x0, exact
// X1[row][i*64+v] bf16, stride 200    : x1 de-interleaved per plane
#define X0_STRIDE 132
#define X1_STRIDE 200

DI void stage_x(const float* __restrict__ x, int b0, float* X0, unsigned short* X1) {
  const int t = threadIdx.x;            // 512 threads
  const int row = t >> 3, l8 = t & 7;
  const float* src = x + (size_t)(b0 + row) * 320;
#pragma unroll
  for (int j = 0; j < 4; ++j) {
    int c = l8 * 4 + j * 32;
    *(f4v*)(&X0[row * X0_STRIDE + c]) = *(const f4v*)(src + c);
  }
#pragma unroll
  for (int j = 0; j < 6; ++j) {
    int c4 = l8 + j * 8;                 // f4v index within the 48 of the x1 region
    f4v v = *(const f4v*)(src + 128 + c4 * 4);
#pragma unroll
    for (int e = 0; e < 4; ++e) {
      int g = c4 * 4 + e;                // 0..191 ;  g = v*3 + i
      X1[row * X1_STRIDE + (g % 3) * 64 + (g / 3)] = (unsigned short)f2bf_rne(v[e]);
    }
  }
}

// ---------------- scalar-path GEMM: C[8192,192] += A(gen) * Wsc ----------------
// block: 64 rows x 192 cols, 8 waves = 4 m-groups x 2 n-halves; split-K 8 (XCD-local)
__global__ __launch_bounds__(512, 4)
void gemm_sc(const float* __restrict__ x, const short* __restrict__ wf,
             float* __restrict__ acc_out) {
  __shared__ float X0[64 * X0_STRIDE];
  __shared__ unsigned short X1[64 * X1_STRIDE];
  const int kb = blockIdx.x & 7;
  const int mt = blockIdx.x >> 3;
  const int b0 = mt * 64;

  stage_x(x, b0, X0, X1);
  __syncthreads();

  const int t = threadIdx.x;
  const int w = t >> 6, lane = t & 63;
  const int mg = w & 3, nh = w >> 2;
  const int q = lane >> 4, r = lane & 15;
  const int row = mg * 16 + r;
  const float* x0r = &X0[row * X0_STRIDE];
  const unsigned short* x1r = &X1[row * X1_STRIDE];

  f4v acc[6];
#pragma unroll
  for (int nf = 0; nf < 6; ++nf) acc[nf] = f4v{0.f, 0.f, 0.f, 0.f};

  const int sBeg = kb * 80, sEnd = sBeg + 80;
  for (int s = sBeg; s < sEnd; ++s) {
    s8v bfr[6];
#pragma unroll
    for (int nf = 0; nf < 6; ++nf)
      bfr[nf] = *(const s8v*)(wf + (((size_t)s * 12 + nh * 6 + nf) * 64 + lane) * 8);

    const int k0 = s * 32;
    u4v pa;
    if (k0 < 16384) {
      // A[m][k] = x0[m][u] * x0[m][v],  k = u*128 + v
      const int u = k0 >> 7;
      const int vb = (k0 & 127) + q * 8;
      const float xu = x0r[u];
      f4v v0 = *(const f4v*)(x0r + vb);
      f4v v1 = *(const f4v*)(x0r + vb + 4);
      pa[0] = rpack(xu * v0.x, xu * v0.y);
      pa[1] = rpack(xu * v0.z, xu * v0.w);
      pa[2] = rpack(xu * v1.x, xu * v1.y);
      pa[3] = rpack(xu * v1.z, xu * v1.w);
    } else {
      // A[m][k] = dot3(x1[m][u], x1[m][v]),  k-16384 = u*64 + v
      const int kk = k0 - 16384;
      const int u = kk >> 6;
      const int vb = (kk & 63) + q * 8;
      float sm[8] = {0.f, 0.f, 0.f, 0.f, 0.f, 0.f, 0.f, 0.f};
#pragma unroll
      for (int i = 0; i < 3; ++i) {
        const float xu = bf2f(x1r[i * 64 + u]);
        i4v p = *(const i4v*)(x1r + i * 64 + vb);
#pragma unroll
        for (int m = 0; m < 4; ++m) {
          sm[2 * m]     += xu * ibitsf(p[m] << 16);
          sm[2 * m + 1] += xu * ibitsf((int)(p[m] & 0xFFFF0000));
        }
      }
      pa[0] = rpack(sm[0], sm[1]);
      pa[1] = rpack(sm[2], sm[3]);
      pa[2] = rpack(sm[4], sm[5]);
      pa[3] = rpack(sm[6], sm[7]);
    }
    s8v afr = __builtin_bit_cast(s8v, pa);
#pragma unroll
    for (int nf = 0; nf < 6; ++nf)
      acc[nf] = __builtin_amdgcn_mfma_f32_16x16x32_bf16(afr, bfr[nf], acc[nf], 0, 0, 0);
  }

#pragma unroll
  for (int nf = 0; nf < 6; ++nf) {
    int n = (nh * 6 + nf) * 16 + r;
#pragma unroll
    for (int reg = 0; reg < 4; ++reg) {
      int rowo = b0 + mg * 16 + q * 4 + reg;
      atomicAdd(&acc_out[(size_t)rowo * NW_ + n], acc[nf][reg]);
    }
  }
}

// ---------------- vector-path GEMM: C[3*8192, 64] += A(gen) * Wvec ----------------
// block: one plane ip, 64 b-rows x 64 cols, 8 waves = 4 m-groups x 2 k-halves; split-K 4
__global__ __launch_bounds__(512, 4)
void gemm_vec(const float* __restrict__ x, const short* __restrict__ wf,
              float* __restrict__ acc_out) {
  __shared__ float X0[64 * X0_STRIDE];
  __shared__ unsigned short X1[64 * X1_STRIDE];
  const int kb = blockIdx.x & 3;
  const int mi = blockIdx.x >> 2;       // mt*3 + ip
  const int ip = mi % 3;
  const int b0 = (mi / 3) * 64;
  const int i1 = (ip + 1) % 3, i2 = (ip + 2) % 3;

  stage_x(x, b0, X0, X1);
  __syncthreads();

  const int t = threadIdx.x;
  const int w = t >> 6, lane = t & 63;
  const int mg = w & 3, kh = w >> 2;
  const int q = lane >> 4, r = lane & 15;
  const int row = mg * 16 + r;
  const float* x0r = &X0[row * X0_STRIDE];
  const unsigned short* x1r = &X1[row * X1_STRIDE];

  f4v acc[4];
#pragma unroll
  for (int nf = 0; nf < 4; ++nf) acc[nf] = f4v{0.f, 0.f, 0.f, 0.f};

  const int sBeg = kb * 96 + kh * 48, sEnd = sBeg + 48;
  for (int s = sBeg; s < sEnd; ++s) {
    s8v bfr[4];
#pragma unroll
    for (int nf = 0; nf < 4; ++nf)
      bfr[nf] = *(const s8v*)(wf + (((size_t)s * 4 + nf) * 64 + lane) * 8);

    const int k0 = s * 32;
    u4v pa;
    if (k0 < 8192) {
      // A = x0[b][u] * x1[b][v][ip],  k = u*64 + v
      const int u = k0 >> 6;
      const int vb = (k0 & 63) + q * 8;
      const float xu = x0r[u];
      i4v p = *(const i4v*)(x1r + ip * 64 + vb);
      float pr[8];
#pragma unroll
      for (int m = 0; m < 4; ++m) {
        pr[2 * m]     = xu * ibitsf(p[m] << 16);
        pr[2 * m + 1] = xu * ibitsf((int)(p[m] & 0xFFFF0000));
      }
      pa[0] = rpack(pr[0], pr[1]);
      pa[1] = rpack(pr[2], pr[3]);
      pa[2] = rpack(pr[4], pr[5]);
      pa[3] = rpack(pr[6], pr[7]);
    } else {
      // A = x1[u][i1]*x1[v][i2] - x1[u][i2]*x1[v][i1]   (cross component ip)
      const int kk = k0 - 8192;
      const int u = kk >> 6;
      const int vb = (kk & 63) + q * 8;
      const float u1 = bf2f(x1r[i1 * 64 + u]);
      const float u2 = bf2f(x1r[i2 * 64 + u]);
      i4v pw = *(const i4v*)(x1r + i2 * 64 + vb);   // plane i2 (multiplied by u1)
      i4v pz = *(const i4v*)(x1r + i1 * 64 + vb);   // plane i1 (multiplied by u2)
      float pr[8];
#pragma unroll
      for (int m = 0; m < 4; ++m) {
        pr[2 * m]     = u1 * ibitsf(pw[m] << 16) - u2 * ibitsf(pz[m] << 16);
        pr[2 * m + 1] = u1 * ibitsf((int)(pw[m] & 0xFFFF0000)) - u2 * ibitsf((int)(pz[m] & 0xFFFF0000));
      }
      pa[0] = rpack(pr[0], pr[1]);
      pa[1] = rpack(pr[2], pr[3]);
      pa[2] = rpack(pr[4], pr[5]);
      pa[3] = rpack(pr[6], pr[7]);
    }
    s8v afr = __builtin_bit_cast(s8v, pa);
#pragma unroll
    for (int nf = 0; nf < 4; ++nf)
      acc[nf] = __builtin_amdgcn_mfma_f32_16x16x32_bf16(afr, bfr[nf], acc[nf], 0, 0, 0);
  }

#pragma unroll
  for (int nf = 0; nf < 4; ++nf) {
    int n = nf * 16 + r;
#pragma unroll
    for (int reg = 0; reg < 4; ++reg) {
      int rowo = ip * B_ + b0 + mg * 16 + q * 4 + reg;
      atomicAdd(&acc_out[(size_t)rowo * 64 + n], acc[nf][reg]);
    }
  }
}

// ---------------- epilogue: silu / sigmoid-gating, interleaved output ----------------
__global__ void epilogue(const float* __restrict__ sc, const float* __restrict__ ve,
                         float* __restrict__ out) {
  int t = blockIdx.x * blockDim.x + threadIdx.x;  // B*192 threads exactly
  int b = t / NW_, c = t % NW_;
  float v = sc[t];
  float sg = 1.0f / (1.0f + __expf(-v));
  if (c < 128) {
    out[(size_t)b * 320 + c] = v * sg;            // silu
  } else {
    int w = c - 128;
#pragma unroll
    for (int i = 0; i < 3; ++i) {
      float vv = ve[((size_t)i * B_ + b) * 64 + w];
      out[(size_t)b * 320 + 128 + w * 3 + i] = vv * sg;
    }
  }
}

// ---------------- launch ----------------
extern "C" void kernel_launch(void* const* d_in, const int* in_sizes, int n_in,
                              void* d_out, int out_size, void* d_ws, size_t ws_size,
                              hipStream_t stream) {
  const float* x    = (const float*)d_in[0];
  const float* w000 = (const float*)d_in[1];
  const float* w110 = (const float*)d_in[2];
  const float* w011 = (const float*)d_in[3];
  const float* w111 = (const float*)d_in[4];
  float* out = (float*)d_out;

  char* ws = (char*)d_ws;
  float* acc_sc = (float*)ws;                     // 8192*192*4  = 6,291,456 B
  float* acc_ve = (float*)(ws + 6291456);         // 3*8192*64*4 = 6,291,456 B
  short* wsc    = (short*)(ws + 12582912);        // 20480*192*2 = 7,864,320 B
  short* wve    = (short*)(ws + 20447232);        // 12288*64*2  = 1,572,864 B
  // total ws use: 22,020,096 B

  (void)hipMemsetAsync(acc_sc, 0, 2 * 6291456, stream);  // zero both accumulators
  prep_wsc <<<1920, 256, 0, stream>>>(w000, w110, wsc);
  prep_wvec<<<384,  256, 0, stream>>>(w011, w111, wve);
  gemm_sc  <<<1024, 512, 0, stream>>>(x, wsc, acc_sc);
  gemm_vec <<<1536, 512, 0, stream>>>(x, wve, acc_ve);
  epilogue <<<6144, 256, 0, stream>>>(acc_sc, acc_ve, out);
}

// Round 3
// 293.107 us; speedup vs baseline: 2.6554x; 1.2102x over previous
//
#include <hip/hip_runtime.h>
#include <cstdint>

// ---------------- problem constants ----------------
static constexpr int B_  = 8192;
static constexpr int NW_ = 192;                 // NS + NV

typedef __attribute__((ext_vector_type(8))) short s8v;
typedef __attribute__((ext_vector_type(4))) float f4v;
typedef __attribute__((ext_vector_type(2))) float f2v;
typedef __attribute__((ext_vector_type(4))) int i4v;
typedef __attribute__((ext_vector_type(4))) unsigned u4v;

#define DI __device__ __forceinline__

DI short f2bf_rne(float f) {
  unsigned u = __builtin_bit_cast(unsigned, f);
  u += 0x7FFFu + ((u >> 16) & 1u);               // round-to-nearest-even
  return (short)(u >> 16);
}
DI float bf2f(unsigned short h) {
  unsigned u = ((unsigned)h) << 16;
  return __builtin_bit_cast(float, u);
}
DI float ibitsf(int u) { return __builtin_bit_cast(float, u); }
DI float plo(int p) { return ibitsf(p << 16); }
DI float phi(int p) { return ibitsf((int)(p & 0xFFFF0000)); }
// pack bf16(lo), bf16(hi) with round-half-up: 2 adds + 1 v_perm
DI unsigned rpack(float lo, float hi) {
  unsigned ua = __builtin_bit_cast(unsigned, lo) + 0x8000u;
  unsigned ub = __builtin_bit_cast(unsigned, hi) + 0x8000u;
  return __builtin_amdgcn_perm(ub, ua, 0x07060302u);
}

// ---------------- prep: scalar-path weights, fragment-packed bf16 ----------------
// Wf[kt][nt(12)][lane(64)][j(8)] = W[k = kt*32 + (lane>>4)*8 + j][n = nt*16 + (lane&15)]
__global__ void prep_wsc(const float* __restrict__ w000, const float* __restrict__ w110,
                         short* __restrict__ wf) {
  int g = blockIdx.x * blockDim.x + threadIdx.x;  // 20480*192/8 threads exactly
  int l = g & 63;
  int nt = (g >> 6) % 12;
  int kt = g / (64 * 12);
  int n = nt * 16 + (l & 15);
  int kbase = kt * 32 + ((l >> 4) << 3);
  const float s000 = 1.0f / (128.0f * 1.41421356237f);   // (1/N0) * inv_sqrt2
  const float s110 = 1.0f / (64.0f * 2.44948974968f);    // (1/(N1*sqrt6 total))
  s8v o;
#pragma unroll
  for (int j = 0; j < 8; ++j) {
    int k = kbase + j;
    float v = (k < 16384) ? w000[(size_t)k * NW_ + n] * s000
                          : w110[(size_t)(k - 16384) * NW_ + n] * s110;
    o[j] = f2bf_rne(v);
  }
  *(s8v*)(wf + (size_t)g * 8) = o;
}

// ---------------- prep: vector-path weights, fragment-packed bf16 ----------------
__global__ void prep_wvec(const float* __restrict__ w011, const float* __restrict__ w111,
                          short* __restrict__ wf) {
  int g = blockIdx.x * blockDim.x + threadIdx.x;  // 12288*64/8 threads exactly
  int l = g & 63;
  int nt = (g >> 6) & 3;
  int kt = g >> 8;
  int n = nt * 16 + (l & 15);
  int kbase = kt * 32 + ((l >> 4) << 3);
  const float sv = 1.0f / 128.0f;  // both v011 and v111 total scales reduce to 1/128
  s8v o;
#pragma unroll
  for (int j = 0; j < 8; ++j) {
    int k = kbase + j;
    float v = (k < 8192) ? w011[(size_t)k * 64 + n] * sv
                         : w111[(size_t)(k - 8192) * 64 + n] * sv;
    o[j] = f2bf_rne(v);
  }
  *(s8v*)(wf + (size_t)g * 8) = o;
}

// ---------------- shared LDS staging: 64 rows of x ----------------
// X0[row][c] f32, stride 132 (16B-aligned rows, 2-way bank reads = free)
// X1[row][i*64+v] bf16, stride 200 (16B-aligned rows, 2-way bank reads)
#define X0_STRIDE 132
#define X1_STRIDE 200

DI void stage_x(const float* __restrict__ x, int b0, float* X0, unsigned short* X1) {
  const int t = threadIdx.x;            // 512 threads
  const int row = t >> 3, l8 = t & 7;
  const float* src = x + (size_t)(b0 + row) * 320;
  // X0: 16 consecutive floats per thread, vectorized write
#pragma unroll
  for (int j = 0; j < 4; ++j) {
    int c = l8 * 16 + j * 4;
    *(f4v*)(&X0[row * X0_STRIDE + c]) = *(const f4v*)(src + c);
  }
  // X1: 24 consecutive floats (8 vectors, v0 = l8*8), de-interleave in registers,
  // write one b128 per plane (replaces 24 scalar ds_write_b16 -> conflicts /8)
  float buf[24];
#pragma unroll
  for (int j = 0; j < 12; ++j) {
    f2v v = *(const f2v*)(src + 128 + l8 * 24 + j * 2);
    buf[2 * j] = v.x; buf[2 * j + 1] = v.y;
  }
#pragma unroll
  for (int i = 0; i < 3; ++i) {
    u4v o;
#pragma unroll
    for (int e = 0; e < 4; ++e)
      o[e] = rpack(buf[(2 * e) * 3 + i], buf[(2 * e + 1) * 3 + i]);
    *(u4v*)(&X1[row * X1_STRIDE + i * 64 + l8 * 8]) = o;
  }
}

// ---------------- A-fragment generators ----------------
DI u4v agen_x0(const float* __restrict__ x0r, int u, int vb) {
  const float xu = x0r[u];
  f4v v0 = *(const f4v*)(x0r + vb);
  f4v v1 = *(const f4v*)(x0r + vb + 4);
  u4v pa;
  pa[0] = rpack(xu * v0.x, xu * v0.y);
  pa[1] = rpack(xu * v0.z, xu * v0.w);
  pa[2] = rpack(xu * v1.x, xu * v1.y);
  pa[3] = rpack(xu * v1.z, xu * v1.w);
  return pa;
}
DI u4v agen_dots(const unsigned short* __restrict__ x1r, int u, int vb) {
  float sm[8] = {0.f, 0.f, 0.f, 0.f, 0.f, 0.f, 0.f, 0.f};
#pragma unroll
  for (int i = 0; i < 3; ++i) {
    const float xu = bf2f(x1r[i * 64 + u]);
    i4v p = *(const i4v*)(x1r + i * 64 + vb);
#pragma unroll
    for (int m = 0; m < 4; ++m) {
      sm[2 * m]     += xu * plo(p[m]);
      sm[2 * m + 1] += xu * phi(p[m]);
    }
  }
  u4v pa;
  pa[0] = rpack(sm[0], sm[1]);
  pa[1] = rpack(sm[2], sm[3]);
  pa[2] = rpack(sm[4], sm[5]);
  pa[3] = rpack(sm[6], sm[7]);
  return pa;
}

// ---------------- scalar-path GEMM: C[8192,192] += A(gen) * Wsc ----------------
// block 64 rows x 192 cols; 8 waves = mg(2) x nh(2) x kh(2); wave = 2 m-frags x 6 n-frags
// split-K 8 total (kb=blockIdx&3 XCD-local x kh); grid 512 = exactly 2 blocks/CU
__global__ __launch_bounds__(512, 4)
void gemm_sc(const float* __restrict__ x, const short* __restrict__ wf,
             float* __restrict__ acc_out) {
  __shared__ float X0[64 * X0_STRIDE];
  __shared__ unsigned short X1[64 * X1_STRIDE];
  const int kb = blockIdx.x & 3;
  const int b0 = (blockIdx.x >> 2) * 64;

  stage_x(x, b0, X0, X1);
  __syncthreads();

  const int t = threadIdx.x;
  const int w = t >> 6, lane = t & 63;
  const int mg = w & 1, nh = (w >> 1) & 1, kh = w >> 2;
  const int q = lane >> 4, r = lane & 15;
  const int rowA = mg * 32 + r;
  const float* x0A = &X0[rowA * X0_STRIDE];
  const float* x0B = &X0[(rowA + 16) * X0_STRIDE];
  const unsigned short* x1A = &X1[rowA * X1_STRIDE];
  const unsigned short* x1B = &X1[(rowA + 16) * X1_STRIDE];

  f4v acc[2][6];
#pragma unroll
  for (int f = 0; f < 2; ++f)
#pragma unroll
    for (int nf = 0; nf < 6; ++nf) acc[f][nf] = f4v{0.f, 0.f, 0.f, 0.f};

  const int sBeg = (kb * 2 + kh) * 80, sEnd = sBeg + 80;
  for (int s = sBeg; s < sEnd; ++s) {
    s8v bfr[6];
#pragma unroll
    for (int nf = 0; nf < 6; ++nf)
      bfr[nf] = *(const s8v*)(wf + (((size_t)s * 12 + nh * 6 + nf) * 64 + lane) * 8);

    const int k0 = s * 32;
    u4v pa[2];
    if (k0 < 16384) {
      const int u = k0 >> 7;
      const int vb = (k0 & 127) + q * 8;
      pa[0] = agen_x0(x0A, u, vb);
      pa[1] = agen_x0(x0B, u, vb);
    } else {
      const int kk = k0 - 16384;
      const int u = kk >> 6;
      const int vb = (kk & 63) + q * 8;
      pa[0] = agen_dots(x1A, u, vb);
      pa[1] = agen_dots(x1B, u, vb);
    }
#pragma unroll
    for (int f = 0; f < 2; ++f) {
      s8v afr = __builtin_bit_cast(s8v, pa[f]);
#pragma unroll
      for (int nf = 0; nf < 6; ++nf)
        acc[f][nf] = __builtin_amdgcn_mfma_f32_16x16x32_bf16(afr, bfr[nf], acc[f][nf], 0, 0, 0);
    }
  }

#pragma unroll
  for (int f = 0; f < 2; ++f)
#pragma unroll
    for (int nf = 0; nf < 6; ++nf) {
      int n = (nh * 6 + nf) * 16 + r;
#pragma unroll
      for (int reg = 0; reg < 4; ++reg) {
        int rowo = b0 + mg * 32 + f * 16 + q * 4 + reg;
        atomicAdd(&acc_out[(size_t)rowo * NW_ + n], acc[f][nf][reg]);
      }
    }
}

// ---------------- vector-path GEMM: C[3*8192, 64] += A(gen) * Wvec ----------------
// block 64 rows x (3 planes x 64 cols) -- 3 planes fused: share B-frags + x1 reads.
// 8 waves = mg(4) x kh(2); wave = 1 m-frag x 3 planes x 4 n-frags = 12 MFMA/step
__global__ __launch_bounds__(512, 4)
void gemm_vec(const float* __restrict__ x, const short* __restrict__ wf,
              float* __restrict__ acc_out) {
  __shared__ float X0[64 * X0_STRIDE];
  __shared__ unsigned short X1[64 * X1_STRIDE];
  const int kb = blockIdx.x & 3;
  const int b0 = (blockIdx.x >> 2) * 64;

  stage_x(x, b0, X0, X1);
  __syncthreads();

  const int t = threadIdx.x;
  const int w = t >> 6, lane = t & 63;
  const int mg = w & 3, kh = w >> 2;
  const int q = lane >> 4, r = lane & 15;
  const int row = mg * 16 + r;
  const float* x0r = &X0[row * X0_STRIDE];
  const unsigned short* x1r = &X1[row * X1_STRIDE];

  f4v acc[3][4];
#pragma unroll
  for (int ip = 0; ip < 3; ++ip)
#pragma unroll
    for (int nf = 0; nf < 4; ++nf) acc[ip][nf] = f4v{0.f, 0.f, 0.f, 0.f};

  const int sBeg = (kb * 2 + kh) * 48, sEnd = sBeg + 48;
  for (int s = sBeg; s < sEnd; ++s) {
    s8v bfr[4];
#pragma unroll
    for (int nf = 0; nf < 4; ++nf)
      bfr[nf] = *(const s8v*)(wf + (((size_t)s * 4 + nf) * 64 + lane) * 8);

    const int k0 = s * 32;
    u4v pa[3];
    if (k0 < 8192) {
      // A[ip] = x0[u] * x1[v][ip],  k = u*64 + v  (xu shared across planes)
      const int u = k0 >> 6;
      const int vb = (k0 & 63) + q * 8;
      const float xu = x0r[u];
#pragma unroll
      for (int i = 0; i < 3; ++i) {
        i4v p = *(const i4v*)(x1r + i * 64 + vb);
#pragma unroll
        for (int m = 0; m < 4; ++m)
          pa[i][m] = rpack(xu * plo(p[m]), xu * phi(p[m]));
      }
    } else {
      // A[ip] = x1[u][ip+1]*x1[v][ip+2] - x1[u][ip+2]*x1[v][ip+1]
      const int kk = k0 - 8192;
      const int u = kk >> 6;
      const int vb = (kk & 63) + q * 8;
      float us[3];
      float pf[3][8];
#pragma unroll
      for (int i = 0; i < 3; ++i) {
        us[i] = bf2f(x1r[i * 64 + u]);
        i4v p = *(const i4v*)(x1r + i * 64 + vb);
#pragma unroll
        for (int m = 0; m < 4; ++m) {
          pf[i][2 * m]     = plo(p[m]);
          pf[i][2 * m + 1] = phi(p[m]);
        }
      }
#pragma unroll
      for (int ip = 0; ip < 3; ++ip) {
        const int i1 = (ip + 1) % 3, i2 = (ip + 2) % 3;
#pragma unroll
        for (int e = 0; e < 4; ++e) {
          float lo = us[i1] * pf[i2][2 * e]     - us[i2] * pf[i1][2 * e];
          float hi = us[i1] * pf[i2][2 * e + 1] - us[i2] * pf[i1][2 * e + 1];
          pa[ip][e] = rpack(lo, hi);
        }
      }
    }
#pragma unroll
    for (int ip = 0; ip < 3; ++ip) {
      s8v afr = __builtin_bit_cast(s8v, pa[ip]);
#pragma unroll
      for (int nf = 0; nf < 4; ++nf)
        acc[ip][nf] = __builtin_amdgcn_mfma_f32_16x16x32_bf16(afr, bfr[nf], acc[ip][nf], 0, 0, 0);
    }
  }

#pragma unroll
  for (int ip = 0; ip < 3; ++ip)
#pragma unroll
    for (int nf = 0; nf < 4; ++nf) {
      int n = nf * 16 + r;
#pragma unroll
      for (int reg = 0; reg < 4; ++reg) {
        int rowo = ip * B_ + b0 + mg * 16 + q * 4 + reg;
        atomicAdd(&acc_out[(size_t)rowo * 64 + n], acc[ip][nf][reg]);
      }
    }
}

// ---------------- epilogue: silu / sigmoid-gating, interleaved output ----------------
__global__ void epilogue(const float* __restrict__ sc, const float* __restrict__ ve,
                         float* __restrict__ out) {
  int t = blockIdx.x * blockDim.x + threadIdx.x;  // B*192 threads exactly
  int b = t / NW_, c = t % NW_;
  float v = sc[t];
  float sg = 1.0f / (1.0f + __expf(-v));
  if (c < 128) {
    out[(size_t)b * 320 + c] = v * sg;            // silu
  } else {
    int w = c - 128;
#pragma unroll
    for (int i = 0; i < 3; ++i) {
      float vv = ve[((size_t)i * B_ + b) * 64 + w];
      out[(size_t)b * 320 + 128 + w * 3 + i] = vv * sg;
    }
  }
}

// ---------------- launch ----------------
extern "C" void kernel_launch(void* const* d_in, const int* in_sizes, int n_in,
                              void* d_out, int out_size, void* d_ws, size_t ws_size,
                              hipStream_t stream) {
  const float* x    = (const float*)d_in[0];
  const float* w000 = (const float*)d_in[1];
  const float* w110 = (const float*)d_in[2];
  const float* w011 = (const float*)d_in[3];
  const float* w111 = (const float*)d_in[4];
  float* out = (float*)d_out;

  char* ws = (char*)d_ws;
  float* acc_sc = (float*)ws;                     // 8192*192*4  = 6,291,456 B
  float* acc_ve = (float*)(ws + 6291456);         // 3*8192*64*4 = 6,291,456 B
  short* wsc    = (short*)(ws + 12582912);        // 20480*192*2 = 7,864,320 B
  short* wve    = (short*)(ws + 20447232);        // 12288*64*2  = 1,572,864 B
  // total ws use: 22,020,096 B

  (void)hipMemsetAsync(acc_sc, 0, 2 * 6291456, stream);  // zero both accumulators
  prep_wsc <<<1920, 256, 0, stream>>>(w000, w110, wsc);
  prep_wvec<<<384,  256, 0, stream>>>(w011, w111, wve);
  gemm_sc  <<<512, 512, 0, stream>>>(x, wsc, acc_sc);
  gemm_vec <<<512, 512, 0, stream>>>(x, wve, acc_ve);
  epilogue <<<6144, 256, 0, stream>>>(acc_sc, acc_ve, out);
}